// Round 13
// baseline (376.014 us; speedup 1.0000x reference)
//
#include <hip/hip_runtime.h>

#define S_LEN 2048
#define NHEAD 24
#define CDIM 64
#define DDIM 256

typedef _Float16 f16x8 __attribute__((ext_vector_type(8)));
typedef float f32x4 __attribute__((ext_vector_type(4)));

__device__ __forceinline__ ushort f2h(float f) {
    _Float16 h = (_Float16)f;
    return __builtin_bit_cast(ushort, h);
}
__device__ __forceinline__ uint pkh(float a, float b) {
    auto v = __builtin_amdgcn_cvt_pkrtz(a, b);   // __fp16 ext_vector(2)
    return __builtin_bit_cast(uint, v);
}
__device__ __forceinline__ uint pk2(float a, float b) {   // RTN pack (epilogue)
    return (uint)f2h(a) | ((uint)f2h(b) << 16);
}

// pack 8 consecutive f32 -> 8 f16 (register ops only)
__device__ __forceinline__ int4 cvt8(const float* __restrict__ p) {
    float4 a = *(const float4*)p;
    float4 b = *(const float4*)(p + 4);
    f16x8 h;
    h[0] = (_Float16)a.x; h[1] = (_Float16)a.y;
    h[2] = (_Float16)a.z; h[3] = (_Float16)a.w;
    h[4] = (_Float16)b.x; h[5] = (_Float16)b.y;
    h[6] = (_Float16)b.z; h[7] = (_Float16)b.w;
    return __builtin_bit_cast(int4, h);
}

// async global->LDS, 16B per lane; LDS dest = wave-uniform base + lane*16
__device__ __forceinline__ void gload16(const void* g, void* l) {
    __builtin_amdgcn_global_load_lds(
        (const __attribute__((address_space(1))) void*)g,
        (__attribute__((address_space(3))) void*)l, 16, 0, 0);
}

// log2(e)/sqrt(num_heads=8): folded into K at projection time
#define SCALE_K 0.51006973f

// Fused prep: zero out (131072 float4) | nodes->f16 (65536 int4) | W_val->f16 (196608 int4)
__global__ __launch_bounds__(256) void prep_kernel(
    const float* __restrict__ nodes, const float* __restrict__ W_val,
    float* __restrict__ out, ushort* __restrict__ nodes16, ushort* __restrict__ Wval16)
{
    int idx = blockIdx.x * 256 + threadIdx.x;
    if (idx < 131072) {
        ((float4*)out)[idx] = float4{0.f, 0.f, 0.f, 0.f};
    } else if (idx < 196608) {
        int i = idx - 131072;
        *(int4*)&nodes16[i * 8] = cvt8(&nodes[i * 8]);
    } else {
        int i = idx - 196608;
        *(int4*)&Wval16[i * 8] = cvt8(&W_val[i * 8]);
    }
}

// ---- val GEMM: 128x128 tile, BK=64, global_load_lds staging + coalesced
// LDS-transpose epilogue (R28 build, verified 239.1us / absmax .0078).
__global__ __launch_bounds__(256) void val_kernel(
    const ushort* __restrict__ nodes16, const ushort* __restrict__ Wval16,
    const float* __restrict__ b_val, ushort* __restrict__ Vt)
{
    __shared__ ushort Asub[128 * 64];
    __shared__ ushort Wsub[128 * 64];
    __shared__ uint   Tt[64 * 68];       // 17.4KB transpose buffer
    const int tid = threadIdx.x;
    const int wave = tid >> 6, lane = tid & 63;
    const int g = lane >> 4, c = lane & 15;
    const int wm = wave & 1, wn = wave >> 1;
    const int m0 = (blockIdx.x / 48) * 128, n0 = (blockIdx.x % 48) * 128;
    const int K = 256;
    const int x = c & 7;                 // read-side swizzle key (= row&7)

    f32x4 acc[16];
#pragma unroll
    for (int t = 0; t < 16; t++) acc[t] = f32x4{0, 0, 0, 0};

    for (int k0 = 0; k0 < K; k0 += 64) {
        __syncthreads();
#pragma unroll
        for (int q = 0; q < 4; q++) {
            const int r0 = wave * 32 + q * 8;          // chunk base row
            const int row = r0 + (lane >> 3);
            const int sl = lane & 7;
            const int sc = ((sl ^ (row & 7)) * 8);
            gload16(&nodes16[(m0 + row) * K + k0 + sc], &Asub[r0 * 64]);
            gload16(&Wval16[(n0 + row) * K + k0 + sc], &Wsub[r0 * 64]);
        }
        __syncthreads();

        f16x8 af0[4], af1[4];
#pragma unroll
        for (int mt = 0; mt < 4; mt++) {
            const int row = wm * 64 + mt * 16 + c;
            af0[mt] = *(const f16x8*)&Asub[row * 64 + ((g ^ x) * 8)];
            af1[mt] = *(const f16x8*)&Asub[row * 64 + (((g + 4) ^ x) * 8)];
        }
#pragma unroll
        for (int nt = 0; nt < 4; nt++) {
            const int row = wn * 64 + nt * 16 + c;
            f16x8 bf0 = *(const f16x8*)&Wsub[row * 64 + ((g ^ x) * 8)];
            f16x8 bf1 = *(const f16x8*)&Wsub[row * 64 + (((g + 4) ^ x) * 8)];
#pragma unroll
            for (int mt = 0; mt < 4; mt++) {
                acc[mt * 4 + nt] = __builtin_amdgcn_mfma_f32_16x16x32_f16(af0[mt], bf0, acc[mt * 4 + nt], 0, 0, 0);
                acc[mt * 4 + nt] = __builtin_amdgcn_mfma_f32_16x16x32_f16(af1[mt], bf1, acc[mt * 4 + nt], 0, 0, 0);
            }
        }
    }

    // coalesced epilogue: two n-half passes through LDS transpose
#pragma unroll
    for (int p = 0; p < 2; ++p) {
        __syncthreads();
        if (wn == p) {
#pragma unroll
            for (int nt = 0; nt < 4; nt++) {
                const int nl = nt * 16 + c;            // 0..63 within this half
                const int n = n0 + p * 64 + nl;
                const float bv = b_val[n];
#pragma unroll
                for (int mt = 0; mt < 4; mt++) {
                    const int m2 = wm * 32 + mt * 8 + g * 2;   // uint index (m/2)
                    f32x4 v = acc[mt * 4 + nt];
                    Tt[nl * 68 + m2]     = pk2(v[0] + bv, v[1] + bv);
                    Tt[nl * 68 + m2 + 1] = pk2(v[2] + bv, v[3] + bv);
                }
            }
        }
        __syncthreads();
        {
            const int row = tid >> 2, q = tid & 3;
            const int n = n0 + p * 64 + row;
            const int h = n >> 8, d = n & 255;
            ushort* dst = &Vt[(h * DDIM + d) * S_LEN + m0 + q * 32];
            const uint* src = &Tt[row * 68 + q * 16];
#pragma unroll
            for (int k = 0; k < 4; k++) {
                *(int4*)(dst + k * 8) = *(const int4*)(src + k * 4);
            }
        }
    }
}

// ---- kq GEMM: 64x64 tile, BK=64 (R24-verified body)
__global__ __launch_bounds__(256) void kq_kernel(
    const float* __restrict__ nodes, const float* __restrict__ W_nodes,
    const float* __restrict__ b_nodes,
    const float* __restrict__ aux, const float* __restrict__ W_aux,
    const float* __restrict__ b_aux,
    ushort* __restrict__ Kbuf, ushort* __restrict__ Qbuf)
{
    __shared__ ushort Asub[64 * 72];
    __shared__ ushort Wsub[64 * 72];
    const int tid = threadIdx.x;
    const int wave = tid >> 6, lane = tid & 63;
    const int g = lane >> 4, c = lane & 15;
    const int sub = blockIdx.x;
    const float *A, *W, *b;
    int K, hbase;
    if (sub < 512) { A = nodes; W = W_nodes; b = b_nodes; K = 256; hbase = 0; }
    else           { A = aux;   W = W_aux;   b = b_aux;   K = 64;  hbase = 8; }
    const int t5 = sub & 511;
    const int m0 = (t5 >> 4) * 64, n0 = (t5 & 15) * 64;
    const int srow = tid >> 2;           // 0..63
    const int sc0 = (tid & 3) * 16;      // 0,16,32,48

    f32x4 acc[4] = {f32x4{0,0,0,0}, f32x4{0,0,0,0}, f32x4{0,0,0,0}, f32x4{0,0,0,0}};

    for (int k0 = 0; k0 < K; k0 += 64) {
        __syncthreads();
        *(int4*)&Asub[srow * 72 + sc0]     = cvt8(&A[(m0 + srow) * K + k0 + sc0]);
        *(int4*)&Asub[srow * 72 + sc0 + 8] = cvt8(&A[(m0 + srow) * K + k0 + sc0 + 8]);
        *(int4*)&Wsub[srow * 72 + sc0]     = cvt8(&W[(n0 + srow) * K + k0 + sc0]);
        *(int4*)&Wsub[srow * 72 + sc0 + 8] = cvt8(&W[(n0 + srow) * K + k0 + sc0 + 8]);
        __syncthreads();
        const ushort* Ar = &Asub[(wave * 16 + c) * 72 + g * 8];
        f16x8 af0 = *(const f16x8*)Ar;
        f16x8 af1 = *(const f16x8*)(Ar + 32);
#pragma unroll
        for (int t = 0; t < 4; t++) {
            const ushort* Wr = &Wsub[(t * 16 + c) * 72 + g * 8];
            f16x8 bf0 = *(const f16x8*)Wr;
            f16x8 bf1 = *(const f16x8*)(Wr + 32);
            acc[t] = __builtin_amdgcn_mfma_f32_16x16x32_f16(af0, bf0, acc[t], 0, 0, 0);
            acc[t] = __builtin_amdgcn_mfma_f32_16x16x32_f16(af1, bf1, acc[t], 0, 0, 0);
        }
    }

#pragma unroll
    for (int t = 0; t < 4; t++) {
        int n = n0 + t * 16 + c;
        float bv = b[n];
        int h = hbase + (n >> 7);
        int cc = n & 127;
        float sc = (cc < 64) ? SCALE_K : 1.0f;   // fold softmax scale into K
#pragma unroll
        for (int r = 0; r < 4; r++) {
            int m = m0 + wave * 16 + g * 4 + r;
            ushort u = f2h((acc[t][r] + bv) * sc);
            if (cc < 64) Kbuf[(h * S_LEN + m) * CDIM + cc] = u;
            else         Qbuf[(h * S_LEN + m) * CDIM + cc - 64] = u;
        }
    }
}

// ---- rot projection: pure-register, no LDS
__global__ __launch_bounds__(256) void rot_kernel(
    const float* __restrict__ rot, const float* __restrict__ W_rot,
    ushort* __restrict__ Kbuf, ushort* __restrict__ Qbuf)
{
    int u = blockIdx.x * 256 + threadIdx.x;  // 0..262143
    int i = u >> 7;                          // row 0..2047
    int n8 = (u & 127) * 8;                  // base n, multiple of 8
    int cc = n8 & 127;                       // all 8 elems in same K/Q half
    float sc = (cc < 64) ? SCALE_K : 1.0f;
    float4 r = *(const float4*)&rot[i * 4];
    ushort pv[8];
#pragma unroll
    for (int q = 0; q < 8; q++) {
        float4 w = *(const float4*)&W_rot[(n8 + q) * 4];
        pv[q] = f2h((r.x * w.x + r.y * w.y + r.z * w.z + r.w * w.w) * sc);
    }
    int h = 16 + (n8 >> 7);
    int4 pkt = *(int4*)pv;
    if (cc < 64) *(int4*)&Kbuf[(h * S_LEN + i) * CDIM + cc] = pkt;
    else         *(int4*)&Qbuf[(h * S_LEN + i) * CDIM + cc - 64] = pkt;
}

// Flash attention. R17/R18/R20/R22/R23/R26 stack.
// R29: i-tile 64 -> 32 rows. Occupancy was GRID-limited (768 blocks = 3/CU
// exactly); halving the i-tile gives 1536 blocks with 4/CU resident
// (LDS 27.9KB, VGPR ~105 <= (256,4)'s 128 cap). QK+softmax run on waves 0-1
// (16 rows each, identical serial chain); all 4 waves keep their 64-wide
// D-slice for PV with acc halved (8 x f32x4, -32 VGPR). Numerics identical.
__global__ __launch_bounds__(256, 4) void flash_kernel(
    const ushort* __restrict__ Kbuf, const ushort* __restrict__ Qbuf,
    const ushort* __restrict__ Vt, float* __restrict__ out)
{
    __shared__ ushort Qlds[2][64 * 72];
    __shared__ ushort Plds[2][32 * 72];
    __shared__ float  Alds[2][32];
    __shared__ int    Need[2][2] __attribute__((aligned(8)));

    const int tid = threadIdx.x;
    const int wave = tid >> 6, lane = tid & 63;
    const int g = lane >> 4, c = lane & 15;
    // XCD swizzle: lin%8 = XCD; 3 heads per XCD x 64 i-tiles of 32 rows.
    const int lin = blockIdx.y * 64 + blockIdx.x;   // 0..1535
    const int xcd = lin & 7;
    const int slot = lin >> 3;               // 0..191 within this XCD
    const int h = xcd * 3 + (slot >> 6);     // 3 heads per XCD
    const int i0 = (slot & 63) * 32;         // 64 i-tiles of 32 rows per head
    const int ph4 = (slot & 7) * 4;          // tile-order phase (0..28)
    const float THR = 8.0f;                  // defer-max threshold (log2 units)
    const bool qkw = (wave < 2);             // QK/softmax waves

    // K rows for this block: i0 + (wave&1)*16 + c (waves 2-3 load rows 0-31
    // redundantly — in-bounds, unused)
    const ushort* Krow = &Kbuf[(h * S_LEN + i0 + (wave & 1) * 16 + c) * CDIM + g * 8];
    f16x8 ka0 = *(const f16x8*)Krow;
    f16x8 ka1 = *(const f16x8*)(Krow + 32);

    const ushort* Vbase = &Vt[(h * DDIM + wave * 64 + c) * S_LEN + g * 8];
    const ushort* Qh = &Qbuf[h * S_LEN * CDIM];

    const int qr0 = tid >> 3, qc0 = (tid & 7) * 8;   // rows 0..31
    const int qr1 = qr0 + 32;                        // rows 32..63

    const int tt0 = ph4;
    const int tt1 = (ph4 + 1) & 31;
    *(int4*)&Qlds[0][qr0 * 72 + qc0] = *(const int4*)&Qh[(tt0 * 64 + qr0) * CDIM + qc0];
    *(int4*)&Qlds[0][qr1 * 72 + qc0] = *(const int4*)&Qh[(tt0 * 64 + qr1) * CDIM + qc0];
    int4 qn0 = *(const int4*)&Qh[(tt1 * 64 + qr0) * CDIM + qc0];
    int4 qn1 = *(const int4*)&Qh[(tt1 * 64 + qr1) * CDIM + qc0];

    f16x8 vf0[4], vf1[4];
#pragma unroll
    for (int u = 0; u < 4; u++) {
        const ushort* Vr = Vbase + (u * 16) * S_LEN + tt0 * 64;
        vf0[u] = *(const f16x8*)Vr;
        vf1[u] = *(const f16x8*)(Vr + 32);
    }

    f32x4 acc[8];
#pragma unroll
    for (int u = 0; u < 8; u++) acc[u] = f32x4{0, 0, 0, 0};
    float mrow = -1e30f, lrow = 0.f;

    __syncthreads();

    // ---- QK(first tile) + softmax -> Plds[0], Alds[0], Need[0]  (waves 0-1)
    if (qkw) {
        f32x4 Sf[4];
#pragma unroll
        for (int jc = 0; jc < 4; jc++) {
            const ushort* Qr = &Qlds[0][(jc * 16 + c) * 72 + g * 8];
            f16x8 qb0 = *(const f16x8*)Qr;
            f16x8 qb1 = *(const f16x8*)(Qr + 32);
            f32x4 s = {0, 0, 0, 0};
            s = __builtin_amdgcn_mfma_f32_16x16x32_f16(qb0, ka0, s, 0, 0, 0);
            s = __builtin_amdgcn_mfma_f32_16x16x32_f16(qb1, ka1, s, 0, 0, 0);
            Sf[jc] = s;
        }
        float tm = -1e30f;
#pragma unroll
        for (int jc = 0; jc < 4; jc++)
            tm = fmaxf(tm, fmaxf(fmaxf(Sf[jc][0], Sf[jc][1]),
                                 fmaxf(Sf[jc][2], Sf[jc][3])));
        tm = fmaxf(tm, __shfl_xor(tm, 16));
        tm = fmaxf(tm, __shfl_xor(tm, 32));
        const bool need = __any(tm > mrow + THR);
        float nm, alpha;
        if (need) { nm = fmaxf(tm, mrow); alpha = exp2f(mrow - nm); }
        else      { nm = mrow; alpha = 1.0f; }
        if (lane == 0) Need[0][wave] = need ? 1 : 0;
        float rs = 0.f;
#pragma unroll
        for (int jc = 0; jc < 4; jc++) {
            float p0 = exp2f(Sf[jc][0] - nm);
            float p1 = exp2f(Sf[jc][1] - nm);
            float p2 = exp2f(Sf[jc][2] - nm);
            float p3 = exp2f(Sf[jc][3] - nm);
            rs += (p0 + p1) + (p2 + p3);
            uint2 w;
            w.x = pkh(p0, p1);
            w.y = pkh(p2, p3);
            *(uint2*)&Plds[0][(wave * 16 + c) * 72 + jc * 16 + g * 4] = w;
        }
        lrow = lrow * alpha + rs;
        mrow = nm;
        if (g == 0) Alds[0][wave * 16 + c] = alpha;
    }
    *(int4*)&Qlds[1][qr0 * 72 + qc0] = qn0;
    *(int4*)&Qlds[1][qr1 * 72 + qc0] = qn1;

    // ---- main skewed loop: body t does PV(tile t) + QK/softmax(tile t+1)
    for (int t = 0; t < 31; ++t) {
        const int cur = t & 1, nxt = cur ^ 1;
        __syncthreads();   // Plds/Alds/Need[cur] + Qlds[nxt] all published

        if (t < 30) {
            const int tt2 = (ph4 + t + 2) & 31;
            qn0 = *(const int4*)&Qh[(tt2 * 64 + qr0) * CDIM + qc0];
            qn1 = *(const int4*)&Qh[(tt2 * 64 + qr1) * CDIM + qc0];
        }

        // QK(t+1) on waves 0-1
        f32x4 Sf[4];
        if (qkw) {
            __builtin_amdgcn_s_setprio(1);
#pragma unroll
            for (int jc = 0; jc < 4; jc++) {
                const ushort* Qr = &Qlds[nxt][(jc * 16 + c) * 72 + g * 8];
                f16x8 qb0 = *(const f16x8*)Qr;
                f16x8 qb1 = *(const f16x8*)(Qr + 32);
                f32x4 s = {0, 0, 0, 0};
                s = __builtin_amdgcn_mfma_f32_16x16x32_f16(qb0, ka0, s, 0, 0, 0);
                s = __builtin_amdgcn_mfma_f32_16x16x32_f16(qb1, ka1, s, 0, 0, 0);
                Sf[jc] = s;
            }
            __builtin_amdgcn_s_setprio(0);
        }

        // rescale acc for tile t (state published last iteration)
        int2 nf = *(const int2*)&Need[cur][0];
        if (nf.x | nf.y) {
#pragma unroll
            for (int b = 0; b < 2; b++) {
                f32x4 ab = *(const f32x4*)&Alds[cur][b * 16 + g * 4];
#pragma unroll
                for (int u = 0; u < 4; u++) acc[b * 4 + u] *= ab;
            }
        }

        // PV(t): 16 MFMA into acc (all 4 waves, 32 rows x own 64-d slice)
        __builtin_amdgcn_s_setprio(1);
#pragma unroll
        for (int b = 0; b < 2; b++) {
            const ushort* Pr = &Plds[cur][(b * 16 + c) * 72 + g * 8];
            f16x8 pa0 = *(const f16x8*)Pr;
            f16x8 pa1 = *(const f16x8*)(Pr + 32);
#pragma unroll
            for (int u = 0; u < 4; u++) {
                acc[b * 4 + u] = __builtin_amdgcn_mfma_f32_16x16x32_f16(pa0, vf0[u], acc[b * 4 + u], 0, 0, 0);
                acc[b * 4 + u] = __builtin_amdgcn_mfma_f32_16x16x32_f16(pa1, vf1[u], acc[b * 4 + u], 0, 0, 0);
            }
        }
        __builtin_amdgcn_s_setprio(0);

        // prefetch V(tile t+1)
        {
            const int tn = (ph4 + t + 1) & 31;
#pragma unroll
            for (int u = 0; u < 4; u++) {
                const ushort* Vr = Vbase + (u * 16) * S_LEN + tn * 64;
                vf0[u] = *(const f16x8*)Vr;
                vf1[u] = *(const f16x8*)(Vr + 32);
            }
        }

        // softmax(t+1) on waves 0-1 — shuffle-free defer decision
        if (qkw) {
            float tl = -1e30f;
#pragma unroll
            for (int jc = 0; jc < 4; jc++)
                tl = fmaxf(tl, fmaxf(fmaxf(Sf[jc][0], Sf[jc][1]),
                                     fmaxf(Sf[jc][2], Sf[jc][3])));
            const bool need = __any(tl > mrow + THR);
            float nm, alpha;
            if (need) {
                float tm = fmaxf(tl, __shfl_xor(tl, 16));
                tm = fmaxf(tm, __shfl_xor(tm, 32));
                nm = fmaxf(tm, mrow);
                alpha = exp2f(mrow - nm);
            } else { nm = mrow; alpha = 1.0f; }
            if (lane == 0) Need[nxt][wave] = need ? 1 : 0;
            float rs = 0.f;
#pragma unroll
            for (int jc = 0; jc < 4; jc++) {
                float p0 = exp2f(Sf[jc][0] - nm);
                float p1 = exp2f(Sf[jc][1] - nm);
                float p2 = exp2f(Sf[jc][2] - nm);
                float p3 = exp2f(Sf[jc][3] - nm);
                rs += (p0 + p1) + (p2 + p3);
                uint2 w;
                w.x = pkh(p0, p1);
                w.y = pkh(p2, p3);
                *(uint2*)&Plds[nxt][(wave * 16 + c) * 72 + jc * 16 + g * 4] = w;
            }
            lrow = lrow * alpha + rs;
            mrow = nm;
            if (g == 0) Alds[nxt][wave * 16 + c] = alpha;
        }

        if (t < 30) {
            *(int4*)&Qlds[cur][qr0 * 72 + qc0] = qn0;
            *(int4*)&Qlds[cur][qr1 * 72 + qc0] = qn1;
        }
    }

    // ---- epilogue: PV(last tile)
    __syncthreads();
    {
        int2 nf = *(const int2*)&Need[1][0];
        if (nf.x | nf.y) {
#pragma unroll
            for (int b = 0; b < 2; b++) {
                f32x4 ab = *(const f32x4*)&Alds[1][b * 16 + g * 4];
#pragma unroll
                for (int u = 0; u < 4; u++) acc[b * 4 + u] *= ab;
            }
        }
#pragma unroll
        for (int b = 0; b < 2; b++) {
            const ushort* Pr = &Plds[1][(b * 16 + c) * 72 + g * 8];
            f16x8 pa0 = *(const f16x8*)Pr;
            f16x8 pa1 = *(const f16x8*)(Pr + 32);
#pragma unroll
            for (int u = 0; u < 4; u++) {
                acc[b * 4 + u] = __builtin_amdgcn_mfma_f32_16x16x32_f16(pa0, vf0[u], acc[b * 4 + u], 0, 0, 0);
                acc[b * 4 + u] = __builtin_amdgcn_mfma_f32_16x16x32_f16(pa1, vf1[u], acc[b * 4 + u], 0, 0, 0);
            }
        }
    }

    // row-sum: per-lane partial -> reduce across the 4 g-groups once (waves 0-1)
    lrow += __shfl_xor(lrow, 16);
    lrow += __shfl_xor(lrow, 32);

    __syncthreads();
    if (qkw && g == 0) Alds[0][wave * 16 + c] = 1.0f / lrow;
    __syncthreads();
#pragma unroll
    for (int b = 0; b < 2; b++) {
        f32x4 lb = *(const f32x4*)&Alds[0][b * 16 + g * 4];
#pragma unroll
        for (int u = 0; u < 4; u++)
#pragma unroll
            for (int r = 0; r < 4; r++) {
                int i = i0 + b * 16 + g * 4 + r;
                int d = wave * 64 + u * 16 + c;
                atomicAdd(&out[i * DDIM + d], acc[b * 4 + u][r] * lb[r]);
            }
    }
}

extern "C" void kernel_launch(void* const* d_in, const int* in_sizes, int n_in,
                              void* d_out, int out_size, void* d_ws, size_t ws_size,
                              hipStream_t stream) {
    const float *nodes = 0, *aux = 0, *rot = 0, *W_nodes = 0, *b_nodes = 0,
                *W_aux = 0, *b_aux = 0, *W_rot = 0, *W_val = 0, *b_val = 0;
    int i1024[2] = {-1, -1};
    int n1024 = 0;
    for (int i = 0; i < n_in; ++i) {
        const float* p = (const float*)d_in[i];
        switch (in_sizes[i]) {
            case 524288:  nodes   = p; break;
            case 131072:  aux     = p; break;
            case 8192:    rot     = p; break;
            case 262144:  W_nodes = p; break;
            case 65536:   W_aux   = p; break;
            case 4096:    W_rot   = p; break;
            case 1572864: W_val   = p; break;
            case 6144:    b_val   = p; break;
            case 1024:    if (n1024 < 2) i1024[n1024] = i; n1024++; break;
            default: break;
        }
    }
    if (n1024 == 2) {
        b_nodes = (const float*)d_in[i1024[0]];
        b_aux   = (const float*)d_in[i1024[1]];
    }
    if (!nodes || !aux || !rot || !W_nodes || !b_nodes || !W_aux || !b_aux ||
        !W_rot || !W_val || !b_val) {
        nodes   = (const float*)d_in[0];
        aux     = (const float*)d_in[1];
        rot     = (const float*)d_in[2];
        W_nodes = (const float*)d_in[3];
        b_nodes = (const float*)d_in[4];
        W_aux   = (const float*)d_in[5];
        b_aux   = (const float*)d_in[6];
        W_rot   = (const float*)d_in[7];
        W_val   = (const float*)d_in[8];
        b_val   = (const float*)d_in[9];
    }
    float* out = (float*)d_out;

    // ws: pad 2MB | K f16 | Q f16 | Vt f16 | nodes16 (1MB) | Wval16 (3MB)
    float*  Opad = (float*)d_ws;
    ushort* Kbuf = (ushort*)(Opad + S_LEN * DDIM);
    ushort* Qbuf = Kbuf + NHEAD * S_LEN * CDIM;
    ushort* Vt   = Qbuf + NHEAD * S_LEN * CDIM;
    ushort* nodes16 = Vt + NHEAD * DDIM * S_LEN;
    ushort* Wval16  = nodes16 + 524288;

    dim3 blk(256);
    prep_kernel<<<dim3(1536), blk, 0, stream>>>(nodes, W_val, out, nodes16, Wval16);
    val_kernel<<<dim3(768), blk, 0, stream>>>(nodes16, Wval16, b_val, Vt);
    kq_kernel<<<dim3(1024), blk, 0, stream>>>(
        nodes, W_nodes, b_nodes, aux, W_aux, b_aux, Kbuf, Qbuf);
    rot_kernel<<<dim3(1024), blk, 0, stream>>>(rot, W_rot, Kbuf, Qbuf);
    flash_kernel<<<dim3(64, NHEAD), blk, 0, stream>>>(Kbuf, Qbuf, Vt, out);
}

// Round 14
// 233.372 us; speedup vs baseline: 1.6112x; 1.6112x over previous
//
#include <hip/hip_runtime.h>

#define S_LEN 2048
#define NHEAD 24
#define CDIM 64
#define DDIM 256

typedef _Float16 f16x8 __attribute__((ext_vector_type(8)));
typedef float f32x4 __attribute__((ext_vector_type(4)));

__device__ __forceinline__ ushort f2h(float f) {
    _Float16 h = (_Float16)f;
    return __builtin_bit_cast(ushort, h);
}
__device__ __forceinline__ uint pkh(float a, float b) {
    auto v = __builtin_amdgcn_cvt_pkrtz(a, b);   // __fp16 ext_vector(2)
    return __builtin_bit_cast(uint, v);
}
__device__ __forceinline__ uint pk2(float a, float b) {   // RTN pack (epilogue)
    return (uint)f2h(a) | ((uint)f2h(b) << 16);
}

// pack 8 consecutive f32 -> 8 f16 (register ops only)
__device__ __forceinline__ int4 cvt8(const float* __restrict__ p) {
    float4 a = *(const float4*)p;
    float4 b = *(const float4*)(p + 4);
    f16x8 h;
    h[0] = (_Float16)a.x; h[1] = (_Float16)a.y;
    h[2] = (_Float16)a.z; h[3] = (_Float16)a.w;
    h[4] = (_Float16)b.x; h[5] = (_Float16)b.y;
    h[6] = (_Float16)b.z; h[7] = (_Float16)b.w;
    return __builtin_bit_cast(int4, h);
}

// async global->LDS, 16B per lane; LDS dest = wave-uniform base + lane*16
__device__ __forceinline__ void gload16(const void* g, void* l) {
    __builtin_amdgcn_global_load_lds(
        (const __attribute__((address_space(1))) void*)g,
        (__attribute__((address_space(3))) void*)l, 16, 0, 0);
}

// log2(e)/sqrt(num_heads=8): folded into K at projection time
#define SCALE_K 0.51006973f

// Fused prep: zero out (131072 float4) | nodes->f16 (65536 int4) | W_val->f16 (196608 int4)
__global__ __launch_bounds__(256) void prep_kernel(
    const float* __restrict__ nodes, const float* __restrict__ W_val,
    float* __restrict__ out, ushort* __restrict__ nodes16, ushort* __restrict__ Wval16)
{
    int idx = blockIdx.x * 256 + threadIdx.x;
    if (idx < 131072) {
        ((float4*)out)[idx] = float4{0.f, 0.f, 0.f, 0.f};
    } else if (idx < 196608) {
        int i = idx - 131072;
        *(int4*)&nodes16[i * 8] = cvt8(&nodes[i * 8]);
    } else {
        int i = idx - 196608;
        *(int4*)&Wval16[i * 8] = cvt8(&W_val[i * 8]);
    }
}

// ---- val GEMM: 128x128 tile, BK=64, global_load_lds staging (R23-verified)
__global__ __launch_bounds__(256) void val_kernel(
    const ushort* __restrict__ nodes16, const ushort* __restrict__ Wval16,
    const float* __restrict__ b_val, ushort* __restrict__ Vt)
{
    __shared__ ushort Asub[128 * 64];
    __shared__ ushort Wsub[128 * 64];
    const int tid = threadIdx.x;
    const int wave = tid >> 6, lane = tid & 63;
    const int g = lane >> 4, c = lane & 15;
    const int wm = wave & 1, wn = wave >> 1;
    const int m0 = (blockIdx.x / 48) * 128, n0 = (blockIdx.x % 48) * 128;
    const int K = 256;
    const int x = c & 7;                 // read-side swizzle key (= row&7)

    f32x4 acc[16];
#pragma unroll
    for (int t = 0; t < 16; t++) acc[t] = f32x4{0, 0, 0, 0};

    for (int k0 = 0; k0 < K; k0 += 64) {
        __syncthreads();
        // stage: each wave stages 4 chunks of 8 rows (1KB) for A and W.
        // LDS linear [128][64]; source col-slot = sl ^ (row&7).
#pragma unroll
        for (int q = 0; q < 4; q++) {
            const int r0 = wave * 32 + q * 8;          // chunk base row
            const int row = r0 + (lane >> 3);
            const int sl = lane & 7;
            const int sc = ((sl ^ (row & 7)) * 8);
            gload16(&nodes16[(m0 + row) * K + k0 + sc], &Asub[r0 * 64]);
            gload16(&Wval16[(n0 + row) * K + k0 + sc], &Wsub[r0 * 64]);
        }
        __syncthreads();

        f16x8 af0[4], af1[4];
#pragma unroll
        for (int mt = 0; mt < 4; mt++) {
            const int row = wm * 64 + mt * 16 + c;
            af0[mt] = *(const f16x8*)&Asub[row * 64 + ((g ^ x) * 8)];
            af1[mt] = *(const f16x8*)&Asub[row * 64 + (((g + 4) ^ x) * 8)];
        }
#pragma unroll
        for (int nt = 0; nt < 4; nt++) {
            const int row = wn * 64 + nt * 16 + c;
            f16x8 bf0 = *(const f16x8*)&Wsub[row * 64 + ((g ^ x) * 8)];
            f16x8 bf1 = *(const f16x8*)&Wsub[row * 64 + (((g + 4) ^ x) * 8)];
#pragma unroll
            for (int mt = 0; mt < 4; mt++) {
                acc[mt * 4 + nt] = __builtin_amdgcn_mfma_f32_16x16x32_f16(af0[mt], bf0, acc[mt * 4 + nt], 0, 0, 0);
                acc[mt * 4 + nt] = __builtin_amdgcn_mfma_f32_16x16x32_f16(af1[mt], bf1, acc[mt * 4 + nt], 0, 0, 0);
            }
        }
    }

#pragma unroll
    for (int nt = 0; nt < 4; nt++) {
        int n = n0 + wn * 64 + nt * 16 + c;
        float bv = b_val[n];
        int h = n >> 8, d = n & 255;
#pragma unroll
        for (int mt = 0; mt < 4; mt++) {
            int m = m0 + wm * 64 + mt * 16 + g * 4;
            f32x4 v = acc[mt * 4 + nt];
            uint2 pw;
            pw.x = pk2(v[0] + bv, v[1] + bv);
            pw.y = pk2(v[2] + bv, v[3] + bv);
            *(uint2*)&Vt[(h * DDIM + d) * S_LEN + m] = pw;
        }
    }
}

// ---- kq GEMM: 64x64 tile, BK=64 (R24-verified body), own 18.4KB LDS -> 8/CU
__global__ __launch_bounds__(256) void kq_kernel(
    const float* __restrict__ nodes, const float* __restrict__ W_nodes,
    const float* __restrict__ b_nodes,
    const float* __restrict__ aux, const float* __restrict__ W_aux,
    const float* __restrict__ b_aux,
    ushort* __restrict__ Kbuf, ushort* __restrict__ Qbuf)
{
    __shared__ ushort Asub[64 * 72];
    __shared__ ushort Wsub[64 * 72];
    const int tid = threadIdx.x;
    const int wave = tid >> 6, lane = tid & 63;
    const int g = lane >> 4, c = lane & 15;
    const int sub = blockIdx.x;
    const float *A, *W, *b;
    int K, hbase;
    if (sub < 512) { A = nodes; W = W_nodes; b = b_nodes; K = 256; hbase = 0; }
    else           { A = aux;   W = W_aux;   b = b_aux;   K = 64;  hbase = 8; }
    const int t5 = sub & 511;
    const int m0 = (t5 >> 4) * 64, n0 = (t5 & 15) * 64;
    const int srow = tid >> 2;           // 0..63
    const int sc0 = (tid & 3) * 16;      // 0,16,32,48

    f32x4 acc[4] = {f32x4{0,0,0,0}, f32x4{0,0,0,0}, f32x4{0,0,0,0}, f32x4{0,0,0,0}};

    for (int k0 = 0; k0 < K; k0 += 64) {
        __syncthreads();
        *(int4*)&Asub[srow * 72 + sc0]     = cvt8(&A[(m0 + srow) * K + k0 + sc0]);
        *(int4*)&Asub[srow * 72 + sc0 + 8] = cvt8(&A[(m0 + srow) * K + k0 + sc0 + 8]);
        *(int4*)&Wsub[srow * 72 + sc0]     = cvt8(&W[(n0 + srow) * K + k0 + sc0]);
        *(int4*)&Wsub[srow * 72 + sc0 + 8] = cvt8(&W[(n0 + srow) * K + k0 + sc0 + 8]);
        __syncthreads();
        const ushort* Ar = &Asub[(wave * 16 + c) * 72 + g * 8];
        f16x8 af0 = *(const f16x8*)Ar;
        f16x8 af1 = *(const f16x8*)(Ar + 32);
#pragma unroll
        for (int t = 0; t < 4; t++) {
            const ushort* Wr = &Wsub[(t * 16 + c) * 72 + g * 8];
            f16x8 bf0 = *(const f16x8*)Wr;
            f16x8 bf1 = *(const f16x8*)(Wr + 32);
            acc[t] = __builtin_amdgcn_mfma_f32_16x16x32_f16(af0, bf0, acc[t], 0, 0, 0);
            acc[t] = __builtin_amdgcn_mfma_f32_16x16x32_f16(af1, bf1, acc[t], 0, 0, 0);
        }
    }

#pragma unroll
    for (int t = 0; t < 4; t++) {
        int n = n0 + t * 16 + c;
        float bv = b[n];
        int h = hbase + (n >> 7);
        int cc = n & 127;
        float sc = (cc < 64) ? SCALE_K : 1.0f;   // fold softmax scale into K
#pragma unroll
        for (int r = 0; r < 4; r++) {
            int m = m0 + wave * 16 + g * 4 + r;
            ushort u = f2h((acc[t][r] + bv) * sc);
            if (cc < 64) Kbuf[(h * S_LEN + m) * CDIM + cc] = u;
            else         Qbuf[(h * S_LEN + m) * CDIM + cc - 64] = u;
        }
    }
}

// ---- rot projection: pure-register, no LDS -> unconstrained occupancy
__global__ __launch_bounds__(256) void rot_kernel(
    const float* __restrict__ rot, const float* __restrict__ W_rot,
    ushort* __restrict__ Kbuf, ushort* __restrict__ Qbuf)
{
    int u = blockIdx.x * 256 + threadIdx.x;  // 0..262143
    int i = u >> 7;                          // row 0..2047
    int n8 = (u & 127) * 8;                  // base n, multiple of 8
    int cc = n8 & 127;                       // all 8 elems in same K/Q half
    float sc = (cc < 64) ? SCALE_K : 1.0f;
    float4 r = *(const float4*)&rot[i * 4];
    ushort pv[8];
#pragma unroll
    for (int q = 0; q < 8; q++) {
        float4 w = *(const float4*)&W_rot[(n8 + q) * 4];
        pv[q] = f2h((r.x * w.x + r.y * w.y + r.z * w.z + r.w * w.w) * sc);
    }
    int h = 16 + (n8 >> 7);
    int4 pkt = *(int4*)pv;
    if (cc < 64) *(int4*)&Kbuf[(h * S_LEN + i) * CDIM + cc] = pkt;
    else         *(int4*)&Qbuf[(h * S_LEN + i) * CDIM + cc - 64] = pkt;
}

// Flash attention — R26 build, byte-identical (verified 237.6us / absmax .0078).
// R30: reverted R29's 32-row tiles (2x blocks duplicated Q-staging + V streams,
// doubled barriers per unit work, idled waves 2-3 through QK -> MfmaUtil 20->9,
// flash 131->278us). The 64-row / 3-blocks-per-CU balance is a verified local
// optimum: R21a (deeper pipeline, +VGPR) spilled; R29 (smaller tiles, +blocks)
// duplicated streams. Both directions lose.
__global__ __launch_bounds__(256, 3) void flash_kernel(
    const ushort* __restrict__ Kbuf, const ushort* __restrict__ Qbuf,
    const ushort* __restrict__ Vt, float* __restrict__ out)
{
    __shared__ ushort Qlds[2][64 * 72];
    __shared__ ushort Plds[2][64 * 72];
    __shared__ float  Alds[2][64];
    __shared__ int    Need[2][4] __attribute__((aligned(16)));

    const int tid = threadIdx.x;
    const int wave = tid >> 6, lane = tid & 63;
    const int g = lane >> 4, c = lane & 15;
    const int lin = blockIdx.y * 32 + blockIdx.x;
    const int xcd = lin & 7;
    const int slot = lin >> 3;               // 0..95 within this XCD
    const int h = xcd * 3 + (slot >> 5);     // 3 heads per XCD
    const int i0 = (slot & 31) * 64;         // 32 i-tiles per head
    const int ph4 = (slot & 7) * 4;          // tile-order phase (0..28)
    const float THR = 8.0f;                  // defer-max threshold (log2 units)

    const ushort* Krow = &Kbuf[(h * S_LEN + i0 + wave * 16 + c) * CDIM + g * 8];
    f16x8 ka0 = *(const f16x8*)Krow;
    f16x8 ka1 = *(const f16x8*)(Krow + 32);

    const ushort* Vbase = &Vt[(h * DDIM + wave * 64 + c) * S_LEN + g * 8];
    const ushort* Qh = &Qbuf[h * S_LEN * CDIM];

    const int qr0 = tid >> 3, qc0 = (tid & 7) * 8;   // rows 0..31
    const int qr1 = qr0 + 32;                        // rows 32..63

    const int tt0 = ph4;
    const int tt1 = (ph4 + 1) & 31;
    *(int4*)&Qlds[0][qr0 * 72 + qc0] = *(const int4*)&Qh[(tt0 * 64 + qr0) * CDIM + qc0];
    *(int4*)&Qlds[0][qr1 * 72 + qc0] = *(const int4*)&Qh[(tt0 * 64 + qr1) * CDIM + qc0];
    int4 qn0 = *(const int4*)&Qh[(tt1 * 64 + qr0) * CDIM + qc0];
    int4 qn1 = *(const int4*)&Qh[(tt1 * 64 + qr1) * CDIM + qc0];

    f16x8 vf0[4], vf1[4];
#pragma unroll
    for (int u = 0; u < 4; u++) {
        const ushort* Vr = Vbase + (u * 16) * S_LEN + tt0 * 64;
        vf0[u] = *(const f16x8*)Vr;
        vf1[u] = *(const f16x8*)(Vr + 32);
    }

    f32x4 acc[16];
#pragma unroll
    for (int u = 0; u < 16; u++) acc[u] = f32x4{0, 0, 0, 0};
    float mrow = -1e30f, lrow = 0.f;

    __syncthreads();

    // ---- QK(first tile) + softmax -> Plds[0], Alds[0], Need[0]
    {
        f32x4 Sf[4];
#pragma unroll
        for (int jc = 0; jc < 4; jc++) {
            const ushort* Qr = &Qlds[0][(jc * 16 + c) * 72 + g * 8];
            f16x8 qb0 = *(const f16x8*)Qr;
            f16x8 qb1 = *(const f16x8*)(Qr + 32);
            f32x4 s = {0, 0, 0, 0};
            s = __builtin_amdgcn_mfma_f32_16x16x32_f16(qb0, ka0, s, 0, 0, 0);
            s = __builtin_amdgcn_mfma_f32_16x16x32_f16(qb1, ka1, s, 0, 0, 0);
            Sf[jc] = s;
        }
        float tm = -1e30f;
#pragma unroll
        for (int jc = 0; jc < 4; jc++)
            tm = fmaxf(tm, fmaxf(fmaxf(Sf[jc][0], Sf[jc][1]),
                                 fmaxf(Sf[jc][2], Sf[jc][3])));
        tm = fmaxf(tm, __shfl_xor(tm, 16));
        tm = fmaxf(tm, __shfl_xor(tm, 32));
        const bool need = __any(tm > mrow + THR);
        float nm, alpha;
        if (need) { nm = fmaxf(tm, mrow); alpha = exp2f(mrow - nm); }
        else      { nm = mrow; alpha = 1.0f; }
        if (lane == 0) Need[0][wave] = need ? 1 : 0;
        float rs = 0.f;
#pragma unroll
        for (int jc = 0; jc < 4; jc++) {
            float p0 = exp2f(Sf[jc][0] - nm);
            float p1 = exp2f(Sf[jc][1] - nm);
            float p2 = exp2f(Sf[jc][2] - nm);
            float p3 = exp2f(Sf[jc][3] - nm);
            rs += (p0 + p1) + (p2 + p3);
            uint2 w;
            w.x = pkh(p0, p1);
            w.y = pkh(p2, p3);
            *(uint2*)&Plds[0][(wave * 16 + c) * 72 + jc * 16 + g * 4] = w;
        }
        lrow = lrow * alpha + rs;
        mrow = nm;
        if (g == 0) Alds[0][wave * 16 + c] = alpha;
    }
    *(int4*)&Qlds[1][qr0 * 72 + qc0] = qn0;
    *(int4*)&Qlds[1][qr1 * 72 + qc0] = qn1;

    // ---- main skewed loop: body t does PV(tile t) + QK/softmax(tile t+1)
    for (int t = 0; t < 31; ++t) {
        const int cur = t & 1, nxt = cur ^ 1;
        __syncthreads();   // Plds/Alds/Need[cur] + Qlds[nxt] all published

        if (t < 30) {
            const int tt2 = (ph4 + t + 2) & 31;
            qn0 = *(const int4*)&Qh[(tt2 * 64 + qr0) * CDIM + qc0];
            qn1 = *(const int4*)&Qh[(tt2 * 64 + qr1) * CDIM + qc0];
        }

        // QK(t+1)
        f32x4 Sf[4];
        __builtin_amdgcn_s_setprio(1);
#pragma unroll
        for (int jc = 0; jc < 4; jc++) {
            const ushort* Qr = &Qlds[nxt][(jc * 16 + c) * 72 + g * 8];
            f16x8 qb0 = *(const f16x8*)Qr;
            f16x8 qb1 = *(const f16x8*)(Qr + 32);
            f32x4 s = {0, 0, 0, 0};
            s = __builtin_amdgcn_mfma_f32_16x16x32_f16(qb0, ka0, s, 0, 0, 0);
            s = __builtin_amdgcn_mfma_f32_16x16x32_f16(qb1, ka1, s, 0, 0, 0);
            Sf[jc] = s;
        }
        __builtin_amdgcn_s_setprio(0);

        // rescale acc for tile t
        int4 nf = *(const int4*)&Need[cur][0];
        if (nf.x | nf.y | nf.z | nf.w) {
#pragma unroll
            for (int b = 0; b < 4; b++) {
                f32x4 ab = *(const f32x4*)&Alds[cur][b * 16 + g * 4];
#pragma unroll
                for (int u = 0; u < 4; u++) acc[b * 4 + u] *= ab;
            }
        }

        // PV(t): 32 MFMA into acc
        __builtin_amdgcn_s_setprio(1);
#pragma unroll
        for (int b = 0; b < 4; b++) {
            const ushort* Pr = &Plds[cur][(b * 16 + c) * 72 + g * 8];
            f16x8 pa0 = *(const f16x8*)Pr;
            f16x8 pa1 = *(const f16x8*)(Pr + 32);
#pragma unroll
            for (int u = 0; u < 4; u++) {
                acc[b * 4 + u] = __builtin_amdgcn_mfma_f32_16x16x32_f16(pa0, vf0[u], acc[b * 4 + u], 0, 0, 0);
                acc[b * 4 + u] = __builtin_amdgcn_mfma_f32_16x16x32_f16(pa1, vf1[u], acc[b * 4 + u], 0, 0, 0);
            }
        }
        __builtin_amdgcn_s_setprio(0);

        // prefetch V(tile t+1)
        {
            const int tn = (ph4 + t + 1) & 31;
#pragma unroll
            for (int u = 0; u < 4; u++) {
                const ushort* Vr = Vbase + (u * 16) * S_LEN + tn * 64;
                vf0[u] = *(const f16x8*)Vr;
                vf1[u] = *(const f16x8*)(Vr + 32);
            }
        }

        // softmax(t+1) — shuffle-free defer decision
        {
            float tl = -1e30f;
#pragma unroll
            for (int jc = 0; jc < 4; jc++)
                tl = fmaxf(tl, fmaxf(fmaxf(Sf[jc][0], Sf[jc][1]),
                                     fmaxf(Sf[jc][2], Sf[jc][3])));
            const bool need = __any(tl > mrow + THR);
            float nm, alpha;
            if (need) {
                float tm = fmaxf(tl, __shfl_xor(tl, 16));
                tm = fmaxf(tm, __shfl_xor(tm, 32));
                nm = fmaxf(tm, mrow);
                alpha = exp2f(mrow - nm);
            } else { nm = mrow; alpha = 1.0f; }
            if (lane == 0) Need[nxt][wave] = need ? 1 : 0;
            float rs = 0.f;
#pragma unroll
            for (int jc = 0; jc < 4; jc++) {
                float p0 = exp2f(Sf[jc][0] - nm);
                float p1 = exp2f(Sf[jc][1] - nm);
                float p2 = exp2f(Sf[jc][2] - nm);
                float p3 = exp2f(Sf[jc][3] - nm);
                rs += (p0 + p1) + (p2 + p3);
                uint2 w;
                w.x = pkh(p0, p1);
                w.y = pkh(p2, p3);
                *(uint2*)&Plds[nxt][(wave * 16 + c) * 72 + jc * 16 + g * 4] = w;
            }
            lrow = lrow * alpha + rs;
            mrow = nm;
            if (g == 0) Alds[nxt][wave * 16 + c] = alpha;
        }

        if (t < 30) {
            *(int4*)&Qlds[cur][qr0 * 72 + qc0] = qn0;
            *(int4*)&Qlds[cur][qr1 * 72 + qc0] = qn1;
        }
    }

    // ---- epilogue: PV(last tile)
    __syncthreads();
    {
        int4 nf = *(const int4*)&Need[1][0];
        if (nf.x | nf.y | nf.z | nf.w) {
#pragma unroll
            for (int b = 0; b < 4; b++) {
                f32x4 ab = *(const f32x4*)&Alds[1][b * 16 + g * 4];
#pragma unroll
                for (int u = 0; u < 4; u++) acc[b * 4 + u] *= ab;
            }
        }
#pragma unroll
        for (int b = 0; b < 4; b++) {
            const ushort* Pr = &Plds[1][(b * 16 + c) * 72 + g * 8];
            f16x8 pa0 = *(const f16x8*)Pr;
            f16x8 pa1 = *(const f16x8*)(Pr + 32);
#pragma unroll
            for (int u = 0; u < 4; u++) {
                acc[b * 4 + u] = __builtin_amdgcn_mfma_f32_16x16x32_f16(pa0, vf0[u], acc[b * 4 + u], 0, 0, 0);
                acc[b * 4 + u] = __builtin_amdgcn_mfma_f32_16x16x32_f16(pa1, vf1[u], acc[b * 4 + u], 0, 0, 0);
            }
        }
    }

    lrow += __shfl_xor(lrow, 16);
    lrow += __shfl_xor(lrow, 32);

    __syncthreads();
    if (g == 0) Alds[0][wave * 16 + c] = 1.0f / lrow;
    __syncthreads();
#pragma unroll
    for (int b = 0; b < 4; b++) {
        f32x4 lb = *(const f32x4*)&Alds[0][b * 16 + g * 4];
#pragma unroll
        for (int u = 0; u < 4; u++)
#pragma unroll
            for (int r = 0; r < 4; r++) {
                int i = i0 + b * 16 + g * 4 + r;
                int d = wave * 64 + u * 16 + c;
                atomicAdd(&out[i * DDIM + d], acc[b * 4 + u][r] * lb[r]);
            }
    }
}

extern "C" void kernel_launch(void* const* d_in, const int* in_sizes, int n_in,
                              void* d_out, int out_size, void* d_ws, size_t ws_size,
                              hipStream_t stream) {
    const float *nodes = 0, *aux = 0, *rot = 0, *W_nodes = 0, *b_nodes = 0,
                *W_aux = 0, *b_aux = 0, *W_rot = 0, *W_val = 0, *b_val = 0;
    int i1024[2] = {-1, -1};
    int n1024 = 0;
    for (int i = 0; i < n_in; ++i) {
        const float* p = (const float*)d_in[i];
        switch (in_sizes[i]) {
            case 524288:  nodes   = p; break;
            case 131072:  aux     = p; break;
            case 8192:    rot     = p; break;
            case 262144:  W_nodes = p; break;
            case 65536:   W_aux   = p; break;
            case 4096:    W_rot   = p; break;
            case 1572864: W_val   = p; break;
            case 6144:    b_val   = p; break;
            case 1024:    if (n1024 < 2) i1024[n1024] = i; n1024++; break;
            default: break;
        }
    }
    if (n1024 == 2) {
        b_nodes = (const float*)d_in[i1024[0]];
        b_aux   = (const float*)d_in[i1024[1]];
    }
    if (!nodes || !aux || !rot || !W_nodes || !b_nodes || !W_aux || !b_aux ||
        !W_rot || !W_val || !b_val) {
        nodes   = (const float*)d_in[0];
        aux     = (const float*)d_in[1];
        rot     = (const float*)d_in[2];
        W_nodes = (const float*)d_in[3];
        b_nodes = (const float*)d_in[4];
        W_aux   = (const float*)d_in[5];
        b_aux   = (const float*)d_in[6];
        W_rot   = (const float*)d_in[7];
        W_val   = (const float*)d_in[8];
        b_val   = (const float*)d_in[9];
    }
    float* out = (float*)d_out;

    // ws: pad 2MB | K f16 | Q f16 | Vt f16 | nodes16 (1MB) | Wval16 (3MB)
    float*  Opad = (float*)d_ws;
    ushort* Kbuf = (ushort*)(Opad + S_LEN * DDIM);
    ushort* Qbuf = Kbuf + NHEAD * S_LEN * CDIM;
    ushort* Vt   = Qbuf + NHEAD * S_LEN * CDIM;
    ushort* nodes16 = Vt + NHEAD * DDIM * S_LEN;
    ushort* Wval16  = nodes16 + 524288;

    dim3 blk(256);
    prep_kernel<<<dim3(1536), blk, 0, stream>>>(nodes, W_val, out, nodes16, Wval16);
    val_kernel<<<dim3(768), blk, 0, stream>>>(nodes16, Wval16, b_val, Vt);
    kq_kernel<<<dim3(1024), blk, 0, stream>>>(
        nodes, W_nodes, b_nodes, aux, W_aux, b_aux, Kbuf, Qbuf);
    rot_kernel<<<dim3(1024), blk, 0, stream>>>(rot, W_rot, Kbuf, Qbuf);
    flash_kernel<<<dim3(32, NHEAD), blk, 0, stream>>>(Kbuf, Qbuf, Vt, out);
}